// Round 1
// baseline (1011.535 us; speedup 1.0000x reference)
//
#include <hip/hip_runtime.h>

#define LOG2E 1.4426950408889634f
#define TWO_LOG2E 2.8853900817779268f

#if __has_builtin(__builtin_amdgcn_exp2f)
__device__ __forceinline__ float fexp2(float x){ return __builtin_amdgcn_exp2f(x); }
#else
__device__ __forceinline__ float fexp2(float x){ return exp2f(x); }
#endif
#if __has_builtin(__builtin_amdgcn_rcpf)
__device__ __forceinline__ float frcp(float x){ return __builtin_amdgcn_rcpf(x); }
#else
__device__ __forceinline__ float frcp(float x){ return 1.0f/(x); }
#endif

__device__ __forceinline__ float sigm(float x){ return frcp(1.f + fexp2(-LOG2E*x)); }
__device__ __forceinline__ float tanh_fast(float x){ return fmaf(-2.f, frcp(1.f + fexp2(TWO_LOG2E*x)), 1.f); }

// ---------------- embedding: x[n][0:100]=word, [100:128]=tag ----------------
__global__ __launch_bounds__(128) void embed_kernel(
    const int* __restrict__ wid, const int* __restrict__ tgi,
    const float* __restrict__ wemb, const float* __restrict__ temb,
    float* __restrict__ x)
{
    int n = blockIdx.x, j = threadIdx.x;
    float v = (j < 100) ? wemb[wid[n]*100 + j] : temb[tgi[n]*28 + (j-100)];
    x[n*128 + j] = v;
}

// ------------- generic fused-pair GEMM: C[n][r] = scale*(X·W^T + b1 + b2) ----
// grid (8,8,2): 64x64 tiles of a 512x512 output, z selects the (W, bias, C) set
__global__ __launch_bounds__(256) void gemm2(
    const float* __restrict__ X, int ldx,
    const float* __restrict__ Wa, const float* __restrict__ Wb, int ldw, int woffb,
    const float* __restrict__ b1a, const float* __restrict__ b1b,
    const float* __restrict__ b2a, const float* __restrict__ b2b,
    float* __restrict__ Ca, float* __restrict__ Cb,
    int K, float scale)
{
    int z = blockIdx.z;
    const float* W  = z ? Wb  : Wa;
    const float* bb1 = z ? b1b : b1a;
    const float* bb2 = z ? b2b : b2a;
    float* C = z ? Cb : Ca;
    int woff = z ? woffb : 0;

    __shared__ float Xs[64*33];
    __shared__ float Ws[64*33];
    int tid = threadIdx.x;
    int tx = tid & 15, ty = tid >> 4;
    int n0 = blockIdx.y*64, r0 = blockIdx.x*64;
    float acc[4][4] = {};

    for (int k0 = 0; k0 < K; k0 += 32) {
        #pragma unroll
        for (int i = 0; i < 2; ++i) {
            int idx = tid + 256*i;       // 0..511
            int row = idx >> 3, c4 = idx & 7;
            float4 vx = *(const float4*)(X + (n0+row)*ldx + k0 + c4*4);
            float4 vw = *(const float4*)(W + (r0+row)*ldw + woff + k0 + c4*4);
            Xs[row*33 + c4*4+0]=vx.x; Xs[row*33 + c4*4+1]=vx.y; Xs[row*33 + c4*4+2]=vx.z; Xs[row*33 + c4*4+3]=vx.w;
            Ws[row*33 + c4*4+0]=vw.x; Ws[row*33 + c4*4+1]=vw.y; Ws[row*33 + c4*4+2]=vw.z; Ws[row*33 + c4*4+3]=vw.w;
        }
        __syncthreads();
        #pragma unroll 8
        for (int kk = 0; kk < 32; ++kk) {
            float a[4], b[4];
            #pragma unroll
            for (int i = 0; i < 4; ++i) a[i] = Xs[(4*ty+i)*33 + kk];
            #pragma unroll
            for (int j = 0; j < 4; ++j) b[j] = Ws[(4*tx+j)*33 + kk];
            #pragma unroll
            for (int i = 0; i < 4; ++i)
                #pragma unroll
                for (int j = 0; j < 4; ++j)
                    acc[i][j] = fmaf(a[i], b[j], acc[i][j]);
        }
        __syncthreads();
    }
    #pragma unroll
    for (int i = 0; i < 4; ++i)
        #pragma unroll
        for (int j = 0; j < 4; ++j) {
            int r = r0 + 4*tx + j;
            float v = acc[i][j];
            if (bb1) v += bb1[r];
            if (bb2) v += bb2[r];
            C[(n0 + 4*ty + i)*512 + r] = v*scale;
        }
}

// ---------------- LSTM: one block per direction, 512 threads ----------------
// lane tid owns gate-row tid of Whh (128 fp32 weights in VGPRs).
// pre is in TIME order; step s uses t = dir ? 511-s : s.
__global__ __launch_bounds__(512, 2) void lstm_kernel(
    const float* __restrict__ preF, const float* __restrict__ preB,
    const float* __restrict__ WhhF, const float* __restrict__ WhhB,
    const float* __restrict__ h0, const float* __restrict__ c0,
    float* __restrict__ hout, int layer)
{
    const int dir = blockIdx.x;
    const int tid = threadIdx.x;
    const float* Whh = dir ? WhhB : WhhF;
    const float* preD = dir ? preB : preF;

    float w[128];
    {
        const float* wr = Whh + tid*128;
        #pragma unroll
        for (int k4 = 0; k4 < 32; ++k4) {
            float4 v = *(const float4*)(wr + 4*k4);
            w[4*k4+0]=v.x; w[4*k4+1]=v.y; w[4*k4+2]=v.z; w[4*k4+3]=v.w;
        }
    }

    __shared__ __align__(16) float hbuf[128];
    __shared__ __align__(16) float gbuf[512];

    const float* h0d = h0 + (2*layer + dir)*128;
    const float* c0d = c0 + (2*layer + dir)*128;
    float c = (tid < 128) ? c0d[tid] : 0.f;
    if (tid < 128) hbuf[tid] = h0d[tid];
    __syncthreads();

    const int t0 = dir ? 511 : 0;
    const int dt = dir ? -1 : 1;
    float pcur = preD[t0*512 + tid];

    for (int s = 0; s < 512; ++s) {
        int t = t0 + dt*s;
        float pnext = (s < 511) ? preD[(t+dt)*512 + tid] : 0.f;

        float acc0=0.f, acc1=0.f, acc2=0.f, acc3=0.f;
        #pragma unroll
        for (int k4 = 0; k4 < 32; ++k4) {
            float4 hv = *(const float4*)&hbuf[4*k4];   // wave-uniform broadcast
            acc0 = fmaf(hv.x, w[4*k4+0], acc0);
            acc1 = fmaf(hv.y, w[4*k4+1], acc1);
            acc2 = fmaf(hv.z, w[4*k4+2], acc2);
            acc3 = fmaf(hv.w, w[4*k4+3], acc3);
        }
        float g = pcur + ((acc0+acc2) + (acc1+acc3));
        gbuf[tid] = g;
        __syncthreads();

        if (tid < 128) {
            float gi = gbuf[tid];
            float gf = gbuf[tid+128];
            float gg = gbuf[tid+256];
            float go = gbuf[tid+384];
            float iv = sigm(gi), fv = sigm(gf), ov = sigm(go);
            float tg = tanh_fast(gg);
            c = fmaf(fv, c, iv*tg);
            float h = ov * tanh_fast(c);
            hbuf[tid] = h;
            hout[t*256 + dir*128 + tid] = h;
        }
        __syncthreads();
        pcur = pnext;
    }
}

// --------- score kernel: S[n][m] = sum_h w2[h]*tanh(A+B+b1) + b2, diag=0 -----
// Ap/Bp are pre-scaled by 2*log2(e) (b1 folded into Ap), so
// tanh = 1 - 2/(1 + exp2(Ap+Bp)). 32x32 tile / block, grid (16,16).
__global__ __launch_bounds__(256) void score_kernel(
    const float* __restrict__ Ap, const float* __restrict__ Bp,
    const float* __restrict__ W2, const float* __restrict__ b2p,
    float* __restrict__ S)
{
    __shared__ __align__(16) float As[32*132];
    __shared__ __align__(16) float Bs[32*132];
    __shared__ __align__(16) float W2s[128];
    int tid = threadIdx.x;
    int tx = tid & 15, ty = tid >> 4;
    int m0 = blockIdx.x*32, n0 = blockIdx.y*32;
    float acc[2][2] = {{0.f,0.f},{0.f,0.f}};

    for (int hc = 0; hc < 512; hc += 128) {
        #pragma unroll
        for (int i = 0; i < 4; ++i) {
            int idx = tid + 256*i;     // 0..1023 -> 32 rows x 32 float4
            int row = idx >> 5, c4 = idx & 31;
            float4 va = *(const float4*)(Ap + (n0+row)*512 + hc + c4*4);
            float4 vb = *(const float4*)(Bp + (m0+row)*512 + hc + c4*4);
            *(float4*)&As[row*132 + c4*4] = va;
            *(float4*)&Bs[row*132 + c4*4] = vb;
        }
        if (tid < 128) W2s[tid] = W2[hc + tid];
        __syncthreads();

        #pragma unroll 4
        for (int h4 = 0; h4 < 32; ++h4) {
            float4 a0 = *(const float4*)&As[(2*ty    )*132 + 4*h4];
            float4 a1 = *(const float4*)&As[(2*ty + 1)*132 + 4*h4];
            float4 b0 = *(const float4*)&Bs[(tx      )*132 + 4*h4];
            float4 b1 = *(const float4*)&Bs[(tx  + 16)*132 + 4*h4];
            float4 w4 = *(const float4*)&W2s[4*h4];
            float aa[2][4] = {{a0.x,a0.y,a0.z,a0.w},{a1.x,a1.y,a1.z,a1.w}};
            float bb[2][4] = {{b0.x,b0.y,b0.z,b0.w},{b1.x,b1.y,b1.z,b1.w}};
            float ww[4]    = {w4.x,w4.y,w4.z,w4.w};
            #pragma unroll
            for (int q = 0; q < 4; ++q)
                #pragma unroll
                for (int i = 0; i < 2; ++i)
                    #pragma unroll
                    for (int j = 0; j < 2; ++j) {
                        float r = frcp(1.f + fexp2(aa[i][q] + bb[j][q]));
                        acc[i][j] = fmaf(ww[q], fmaf(-2.f, r, 1.f), acc[i][j]);
                    }
        }
        __syncthreads();
    }

    float b2s = b2p[0];
    #pragma unroll
    for (int i = 0; i < 2; ++i)
        #pragma unroll
        for (int j = 0; j < 2; ++j) {
            int gn = n0 + 2*ty + i;
            int gm = m0 + tx + 16*j;
            float v = acc[i][j] + b2s;
            if (gn == gm) v = 0.f;
            S[gn*512 + gm] = v;
        }
}

// ---------------- column sums over n (axis=0) ----------------
__global__ __launch_bounds__(256) void colsum_kernel(const float* __restrict__ S,
                                                     float* __restrict__ csum)
{
    int tid = threadIdx.x;
    int m0 = blockIdx.x*32;
    int a = tid >> 5, m = tid & 31;
    float s = 0.f;
    for (int n = a; n < 512; n += 8) s += S[n*512 + m0 + m];
    __shared__ float ps[8*33];
    ps[a*33 + m] = s;
    __syncthreads();
    if (tid < 32) {
        float t = 0.f;
        #pragma unroll
        for (int k = 0; k < 8; ++k) t += ps[k*33 + tid];
        csum[m0 + tid] = t;
    }
}

// ---------------- row softmax of S[n][m]/csum[m] ----------------
__global__ __launch_bounds__(256) void softmax_kernel(const float* __restrict__ S,
                                                      const float* __restrict__ csum,
                                                      float* __restrict__ out)
{
    int n = blockIdx.x, tid = threadIdx.x;
    float v0 = S[n*512 + tid]       / csum[tid];
    float v1 = S[n*512 + tid + 256] / csum[tid + 256];

    __shared__ float rbuf[4], rbuf2[4];
    int wid = tid >> 6;

    float mx = fmaxf(v0, v1);
    #pragma unroll
    for (int off = 32; off; off >>= 1) mx = fmaxf(mx, __shfl_xor(mx, off, 64));
    if ((tid & 63) == 0) rbuf[wid] = mx;
    __syncthreads();
    mx = fmaxf(fmaxf(rbuf[0], rbuf[1]), fmaxf(rbuf[2], rbuf[3]));

    float e0 = fexp2((v0 - mx)*LOG2E);
    float e1 = fexp2((v1 - mx)*LOG2E);
    float sm = e0 + e1;
    #pragma unroll
    for (int off = 32; off; off >>= 1) sm += __shfl_xor(sm, off, 64);
    if ((tid & 63) == 0) rbuf2[wid] = sm;
    __syncthreads();
    sm = (rbuf2[0] + rbuf2[1]) + (rbuf2[2] + rbuf2[3]);

    float inv = 1.0f / sm;
    out[n*512 + tid]       = e0*inv;
    out[n*512 + tid + 256] = e1*inv;
}

extern "C" void kernel_launch(void* const* d_in, const int* in_sizes, int n_in,
                              void* d_out, int out_size, void* d_ws, size_t ws_size,
                              hipStream_t stream)
{
    const int*   wid  = (const int*)d_in[0];
    const int*   tgi  = (const int*)d_in[1];
    const float* wemb = (const float*)d_in[2];
    const float* temb = (const float*)d_in[3];
    const float* h0   = (const float*)d_in[4];
    const float* c0   = (const float*)d_in[5];
    const float* Wih0f=(const float*)d_in[6],  *Whh0f=(const float*)d_in[7],  *bih0f=(const float*)d_in[8],  *bhh0f=(const float*)d_in[9];
    const float* Wih0b=(const float*)d_in[10], *Whh0b=(const float*)d_in[11], *bih0b=(const float*)d_in[12], *bhh0b=(const float*)d_in[13];
    const float* Wih1f=(const float*)d_in[14], *Whh1f=(const float*)d_in[15], *bih1f=(const float*)d_in[16], *bhh1f=(const float*)d_in[17];
    const float* Wih1b=(const float*)d_in[18], *Whh1b=(const float*)d_in[19], *bih1b=(const float*)d_in[20], *bhh1b=(const float*)d_in[21];
    const float* W1   = (const float*)d_in[22];
    const float* b1   = (const float*)d_in[23];
    const float* W2   = (const float*)d_in[24];
    const float* b2   = (const float*)d_in[25];

    float* ws    = (float*)d_ws;
    float* x     = ws;              // 65536
    float* h0cat = ws + 65536;      // 131072
    float* h1cat = ws + 196608;     // 131072
    float* pA    = ws + 327680;     // 262144  (pre_f, later A')
    float* pB    = ws + 589824;     // 262144  (pre_b, later B')
    float* S     = ws;              // 262144  (aliases x/h0cat region; both dead by then)
    float* csum  = ws + 262144;     // 512     (aliases h1cat tail; dead by then)
    float* out   = (float*)d_out;

    embed_kernel<<<512, 128, 0, stream>>>(wid, tgi, wemb, temb, x);

    gemm2<<<dim3(8,8,2), 256, 0, stream>>>(x, 128, Wih0f, Wih0b, 128, 0,
                                           bih0f, bih0b, bhh0f, bhh0b,
                                           pA, pB, 128, 1.0f);
    lstm_kernel<<<2, 512, 0, stream>>>(pA, pB, Whh0f, Whh0b, h0, c0, h0cat, 0);

    gemm2<<<dim3(8,8,2), 256, 0, stream>>>(h0cat, 256, Wih1f, Wih1b, 256, 0,
                                           bih1f, bih1b, bhh1f, bhh1b,
                                           pA, pB, 256, 1.0f);
    lstm_kernel<<<2, 512, 0, stream>>>(pA, pB, Whh1f, Whh1b, h0, c0, h1cat, 1);

    // A' = 2log2e*(h@W1a^T + b1),  B' = 2log2e*(h@W1b^T)
    gemm2<<<dim3(8,8,2), 256, 0, stream>>>(h1cat, 256, W1, W1, 512, 256,
                                           b1, nullptr, nullptr, nullptr,
                                           pA, pB, 256, TWO_LOG2E);

    score_kernel<<<dim3(16,16), 256, 0, stream>>>(pA, pB, W2, b2, S);
    colsum_kernel<<<16, 256, 0, stream>>>(S, csum);
    softmax_kernel<<<512, 256, 0, stream>>>(S, csum, out);
}

// Round 2
// 842.275 us; speedup vs baseline: 1.2010x; 1.2010x over previous
//
#include <hip/hip_runtime.h>

#define LOG2E 1.4426950408889634f
#define TWO_LOG2E 2.8853900817779268f

#if __has_builtin(__builtin_amdgcn_exp2f)
__device__ __forceinline__ float fexp2(float x){ return __builtin_amdgcn_exp2f(x); }
#else
__device__ __forceinline__ float fexp2(float x){ return exp2f(x); }
#endif
#if __has_builtin(__builtin_amdgcn_rcpf)
__device__ __forceinline__ float frcp(float x){ return __builtin_amdgcn_rcpf(x); }
#else
__device__ __forceinline__ float frcp(float x){ return 1.0f/(x); }
#endif

__device__ __forceinline__ float sigm(float x){ return frcp(1.f + fexp2(-LOG2E*x)); }
__device__ __forceinline__ float tanh_fast(float x){ return fmaf(-2.f, frcp(1.f + fexp2(TWO_LOG2E*x)), 1.f); }

// DPP cross-lane move (full-rate VALU, no LDS pipe)
template<int CTRL>
__device__ __forceinline__ float dpp_f(float x) {
    return __int_as_float(__builtin_amdgcn_update_dpp(0, __float_as_int(x), CTRL, 0xF, 0xF, true));
}
#define DPP_XOR1  0xB1   // quad_perm(1,0,3,2)
#define DPP_XOR2  0x4E   // quad_perm(2,3,0,1)
#define DPP_HMIR  0x141  // row_half_mirror (swap within 8-lane halves)
#define DPP_BC0   0x00   // quad bcast lane0
#define DPP_BC1   0x55
#define DPP_BC2   0xAA
#define DPP_BC3   0xFF

// ---------------- embedding: x[n][0:100]=word, [100:128]=tag ----------------
__global__ __launch_bounds__(128) void embed_kernel(
    const int* __restrict__ wid, const int* __restrict__ tgi,
    const float* __restrict__ wemb, const float* __restrict__ temb,
    float* __restrict__ x)
{
    int n = blockIdx.x, j = threadIdx.x;
    float v = (j < 100) ? wemb[wid[n]*100 + j] : temb[tgi[n]*28 + (j-100)];
    x[n*128 + j] = v;
}

// ------------- generic fused-pair GEMM: C[n][r] = scale*(X·W^T + b1 + b2) ----
__global__ __launch_bounds__(256) void gemm2(
    const float* __restrict__ X, int ldx,
    const float* __restrict__ Wa, const float* __restrict__ Wb, int ldw, int woffb,
    const float* __restrict__ b1a, const float* __restrict__ b1b,
    const float* __restrict__ b2a, const float* __restrict__ b2b,
    float* __restrict__ Ca, float* __restrict__ Cb,
    int K, float scale)
{
    int z = blockIdx.z;
    const float* W  = z ? Wb  : Wa;
    const float* bb1 = z ? b1b : b1a;
    const float* bb2 = z ? b2b : b2a;
    float* C = z ? Cb : Ca;
    int woff = z ? woffb : 0;

    __shared__ float Xs[64*33];
    __shared__ float Ws[64*33];
    int tid = threadIdx.x;
    int tx = tid & 15, ty = tid >> 4;
    int n0 = blockIdx.y*64, r0 = blockIdx.x*64;
    float acc[4][4] = {};

    for (int k0 = 0; k0 < K; k0 += 32) {
        #pragma unroll
        for (int i = 0; i < 2; ++i) {
            int idx = tid + 256*i;
            int row = idx >> 3, c4 = idx & 7;
            float4 vx = *(const float4*)(X + (n0+row)*ldx + k0 + c4*4);
            float4 vw = *(const float4*)(W + (r0+row)*ldw + woff + k0 + c4*4);
            Xs[row*33 + c4*4+0]=vx.x; Xs[row*33 + c4*4+1]=vx.y; Xs[row*33 + c4*4+2]=vx.z; Xs[row*33 + c4*4+3]=vx.w;
            Ws[row*33 + c4*4+0]=vw.x; Ws[row*33 + c4*4+1]=vw.y; Ws[row*33 + c4*4+2]=vw.z; Ws[row*33 + c4*4+3]=vw.w;
        }
        __syncthreads();
        #pragma unroll 8
        for (int kk = 0; kk < 32; ++kk) {
            float a[4], b[4];
            #pragma unroll
            for (int i = 0; i < 4; ++i) a[i] = Xs[(4*ty+i)*33 + kk];
            #pragma unroll
            for (int j = 0; j < 4; ++j) b[j] = Ws[(4*tx+j)*33 + kk];
            #pragma unroll
            for (int i = 0; i < 4; ++i)
                #pragma unroll
                for (int j = 0; j < 4; ++j)
                    acc[i][j] = fmaf(a[i], b[j], acc[i][j]);
        }
        __syncthreads();
    }
    #pragma unroll
    for (int i = 0; i < 4; ++i)
        #pragma unroll
        for (int j = 0; j < 4; ++j) {
            int r = r0 + 4*tx + j;
            float v = acc[i][j];
            if (bb1) v += bb1[r];
            if (bb2) v += bb2[r];
            C[(n0 + 4*ty + i)*512 + r] = v*scale;
        }
}

// ---------------- LSTM: 1024 threads, 64 weights/thread (register-resident) -
// thread t: cell j = t>>3, col-slice sub = t&7 (cols 16*sub..+16),
// rows {j, j+128, j+256, j+384}. 64 fma/lane; DPP butterfly reduce over the
// 8 sub-lanes; gate sub&3's sigmoid computed per lane, shared via quad DPP
// broadcast. h ping-pongs in LDS -> ONE barrier per step.
__global__ __launch_bounds__(1024, 4) void lstm_kernel(
    const float* __restrict__ preF, const float* __restrict__ preB,
    const float* __restrict__ WhhF, const float* __restrict__ WhhB,
    const float* __restrict__ h0, const float* __restrict__ c0,
    float* __restrict__ hout, int layer)
{
    const int dir = blockIdx.x;
    const int tid = threadIdx.x;
    const int j   = tid >> 3;     // cell 0..127
    const int sub = tid & 7;      // col slice 0..7
    const int q   = sub & 3;      // gate handled by this lane's transcendental
    const float* Whh  = dir ? WhhB : WhhF;
    const float* preD = dir ? preB : preF;

    // ---- load 64 weights, bank-rotated chunk order (rot = sub>>1) ----
    const int rot = sub >> 1;
    float w[4][16];
    {
        const int colbase = sub << 4;
        #pragma unroll
        for (int qq = 0; qq < 4; ++qq) {
            const float* wr = Whh + ((qq << 7) + j)*128 + colbase;
            #pragma unroll
            for (int k = 0; k < 4; ++k) {
                int kk = (k + rot) & 3;
                float4 v = *(const float4*)(wr + 4*kk);
                w[qq][4*k+0]=v.x; w[qq][4*k+1]=v.y; w[qq][4*k+2]=v.z; w[qq][4*k+3]=v.w;
            }
        }
    }

    __shared__ __align__(16) float hbuf[2][128];

    const float* h0d = h0 + (2*layer + dir)*128;
    const float* c0d = c0 + (2*layer + dir)*128;
    float c = c0d[j];
    if (tid < 128) hbuf[0][tid] = h0d[tid];

    // per-lane constants
    const float sc = (q == 2) ? -TWO_LOG2E : -LOG2E;   // gate 2 computes sigm(2*gg)
    const int  prow = (q << 7) + j;                    // pre row for this lane's gate
    const int  t0 = dir ? 511 : 0;
    const int  dt = dir ? -1 : 1;

    // LDS float4 chunk indices (conflict-free: banks {0,16,4,20,8,24,12,28}*4)
    int cidx[4];
    #pragma unroll
    for (int k = 0; k < 4; ++k) cidx[k] = (sub << 2) + ((k + rot) & 3);

    float pcur = preD[t0*512 + prow];
    __syncthreads();

    #pragma unroll 2
    for (int s = 0; s < 512; ++s) {
        const int t  = t0 + dt*s;
        const int tn = (s < 511) ? (t + dt) : t;
        float pnext = preD[tn*512 + prow];

        const int p = s & 1;
        const float4* h4 = (const float4*)hbuf[p];
        float4 hv0 = h4[cidx[0]];
        float4 hv1 = h4[cidx[1]];
        float4 hv2 = h4[cidx[2]];
        float4 hv3 = h4[cidx[3]];

        float acc[4] = {0.f, 0.f, 0.f, 0.f};
        #pragma unroll
        for (int qq = 0; qq < 4; ++qq) {
            acc[qq] = fmaf(hv0.x, w[qq][ 0], acc[qq]);
            acc[qq] = fmaf(hv0.y, w[qq][ 1], acc[qq]);
            acc[qq] = fmaf(hv0.z, w[qq][ 2], acc[qq]);
            acc[qq] = fmaf(hv0.w, w[qq][ 3], acc[qq]);
            acc[qq] = fmaf(hv1.x, w[qq][ 4], acc[qq]);
            acc[qq] = fmaf(hv1.y, w[qq][ 5], acc[qq]);
            acc[qq] = fmaf(hv1.z, w[qq][ 6], acc[qq]);
            acc[qq] = fmaf(hv1.w, w[qq][ 7], acc[qq]);
            acc[qq] = fmaf(hv2.x, w[qq][ 8], acc[qq]);
            acc[qq] = fmaf(hv2.y, w[qq][ 9], acc[qq]);
            acc[qq] = fmaf(hv2.z, w[qq][10], acc[qq]);
            acc[qq] = fmaf(hv2.w, w[qq][11], acc[qq]);
            acc[qq] = fmaf(hv3.x, w[qq][12], acc[qq]);
            acc[qq] = fmaf(hv3.y, w[qq][13], acc[qq]);
            acc[qq] = fmaf(hv3.z, w[qq][14], acc[qq]);
            acc[qq] = fmaf(hv3.w, w[qq][15], acc[qq]);
        }

        // butterfly all-reduce across the 8 sub-lanes (DPP, full-rate VALU)
        #pragma unroll
        for (int qq = 0; qq < 4; ++qq) {
            acc[qq] += dpp_f<DPP_XOR1>(acc[qq]);
            acc[qq] += dpp_f<DPP_XOR2>(acc[qq]);
            acc[qq] += dpp_f<DPP_HMIR>(acc[qq]);
        }

        // this lane's gate pre-activation
        float a01 = (q & 1) ? acc[1] : acc[0];
        float a23 = (q & 1) ? acc[3] : acc[2];
        float sel = (q & 2) ? a23 : a01;
        float xg  = (sel + pcur) * sc;
        float sv  = frcp(1.f + fexp2(xg));   // sigm(gate) (gate2: sigm(2*gg))

        // share the four gate values within each quad
        float vi = dpp_f<DPP_BC0>(sv);
        float vf = dpp_f<DPP_BC1>(sv);
        float vg = dpp_f<DPP_BC2>(sv);
        float vo = dpp_f<DPP_BC3>(sv);

        float tg = fmaf(2.f, vg, -1.f);          // tanh(gg)
        c = fmaf(vf, c, vi*tg);
        float e  = fexp2(TWO_LOG2E * c);
        float th = fmaf(-2.f, frcp(1.f + e), 1.f); // tanh(c)
        float h  = vo * th;

        if (sub == 0) {
            hbuf[p ^ 1][j] = h;
            hout[t*256 + dir*128 + j] = h;
        }
        __syncthreads();
        pcur = pnext;
    }
}

// --------- score kernel: S[n][m] = sum_h w2[h]*tanh(A+B+b1) + b2, diag=0 -----
__global__ __launch_bounds__(256) void score_kernel(
    const float* __restrict__ Ap, const float* __restrict__ Bp,
    const float* __restrict__ W2, const float* __restrict__ b2p,
    float* __restrict__ S)
{
    __shared__ __align__(16) float As[32*132];
    __shared__ __align__(16) float Bs[32*132];
    __shared__ __align__(16) float W2s[128];
    int tid = threadIdx.x;
    int tx = tid & 15, ty = tid >> 4;
    int m0 = blockIdx.x*32, n0 = blockIdx.y*32;
    float acc[2][2] = {{0.f,0.f},{0.f,0.f}};

    for (int hc = 0; hc < 512; hc += 128) {
        #pragma unroll
        for (int i = 0; i < 4; ++i) {
            int idx = tid + 256*i;
            int row = idx >> 5, c4 = idx & 31;
            float4 va = *(const float4*)(Ap + (n0+row)*512 + hc + c4*4);
            float4 vb = *(const float4*)(Bp + (m0+row)*512 + hc + c4*4);
            *(float4*)&As[row*132 + c4*4] = va;
            *(float4*)&Bs[row*132 + c4*4] = vb;
        }
        if (tid < 128) W2s[tid] = W2[hc + tid];
        __syncthreads();

        #pragma unroll 4
        for (int h4 = 0; h4 < 32; ++h4) {
            float4 a0 = *(const float4*)&As[(2*ty    )*132 + 4*h4];
            float4 a1 = *(const float4*)&As[(2*ty + 1)*132 + 4*h4];
            float4 b0 = *(const float4*)&Bs[(tx      )*132 + 4*h4];
            float4 b1 = *(const float4*)&Bs[(tx  + 16)*132 + 4*h4];
            float4 w4 = *(const float4*)&W2s[4*h4];
            float aa[2][4] = {{a0.x,a0.y,a0.z,a0.w},{a1.x,a1.y,a1.z,a1.w}};
            float bb[2][4] = {{b0.x,b0.y,b0.z,b0.w},{b1.x,b1.y,b1.z,b1.w}};
            float ww[4]    = {w4.x,w4.y,w4.z,w4.w};
            #pragma unroll
            for (int qi = 0; qi < 4; ++qi)
                #pragma unroll
                for (int i = 0; i < 2; ++i)
                    #pragma unroll
                    for (int jj = 0; jj < 2; ++jj) {
                        float r = frcp(1.f + fexp2(aa[i][qi] + bb[jj][qi]));
                        acc[i][jj] = fmaf(ww[qi], fmaf(-2.f, r, 1.f), acc[i][jj]);
                    }
        }
        __syncthreads();
    }

    float b2s = b2p[0];
    #pragma unroll
    for (int i = 0; i < 2; ++i)
        #pragma unroll
        for (int jj = 0; jj < 2; ++jj) {
            int gn = n0 + 2*ty + i;
            int gm = m0 + tx + 16*jj;
            float v = acc[i][jj] + b2s;
            if (gn == gm) v = 0.f;
            S[gn*512 + gm] = v;
        }
}

// ---------------- column sums over n (axis=0) ----------------
__global__ __launch_bounds__(256) void colsum_kernel(const float* __restrict__ S,
                                                     float* __restrict__ csum)
{
    int tid = threadIdx.x;
    int m0 = blockIdx.x*32;
    int a = tid >> 5, m = tid & 31;
    float s = 0.f;
    for (int n = a; n < 512; n += 8) s += S[n*512 + m0 + m];
    __shared__ float ps[8*33];
    ps[a*33 + m] = s;
    __syncthreads();
    if (tid < 32) {
        float t = 0.f;
        #pragma unroll
        for (int k = 0; k < 8; ++k) t += ps[k*33 + tid];
        csum[m0 + tid] = t;
    }
}

// ---------------- row softmax of S[n][m]/csum[m] ----------------
__global__ __launch_bounds__(256) void softmax_kernel(const float* __restrict__ S,
                                                      const float* __restrict__ csum,
                                                      float* __restrict__ out)
{
    int n = blockIdx.x, tid = threadIdx.x;
    float v0 = S[n*512 + tid]       / csum[tid];
    float v1 = S[n*512 + tid + 256] / csum[tid + 256];

    __shared__ float rbuf[4], rbuf2[4];
    int wid = tid >> 6;

    float mx = fmaxf(v0, v1);
    #pragma unroll
    for (int off = 32; off; off >>= 1) mx = fmaxf(mx, __shfl_xor(mx, off, 64));
    if ((tid & 63) == 0) rbuf[wid] = mx;
    __syncthreads();
    mx = fmaxf(fmaxf(rbuf[0], rbuf[1]), fmaxf(rbuf[2], rbuf[3]));

    float e0 = fexp2((v0 - mx)*LOG2E);
    float e1 = fexp2((v1 - mx)*LOG2E);
    float sm = e0 + e1;
    #pragma unroll
    for (int off = 32; off; off >>= 1) sm += __shfl_xor(sm, off, 64);
    if ((tid & 63) == 0) rbuf2[wid] = sm;
    __syncthreads();
    sm = (rbuf2[0] + rbuf2[1]) + (rbuf2[2] + rbuf2[3]);

    float inv = 1.0f / sm;
    out[n*512 + tid]       = e0*inv;
    out[n*512 + tid + 256] = e1*inv;
}

extern "C" void kernel_launch(void* const* d_in, const int* in_sizes, int n_in,
                              void* d_out, int out_size, void* d_ws, size_t ws_size,
                              hipStream_t stream)
{
    const int*   wid  = (const int*)d_in[0];
    const int*   tgi  = (const int*)d_in[1];
    const float* wemb = (const float*)d_in[2];
    const float* temb = (const float*)d_in[3];
    const float* h0   = (const float*)d_in[4];
    const float* c0   = (const float*)d_in[5];
    const float* Wih0f=(const float*)d_in[6],  *Whh0f=(const float*)d_in[7],  *bih0f=(const float*)d_in[8],  *bhh0f=(const float*)d_in[9];
    const float* Wih0b=(const float*)d_in[10], *Whh0b=(const float*)d_in[11], *bih0b=(const float*)d_in[12], *bhh0b=(const float*)d_in[13];
    const float* Wih1f=(const float*)d_in[14], *Whh1f=(const float*)d_in[15], *bih1f=(const float*)d_in[16], *bhh1f=(const float*)d_in[17];
    const float* Wih1b=(const float*)d_in[18], *Whh1b=(const float*)d_in[19], *bih1b=(const float*)d_in[20], *bhh1b=(const float*)d_in[21];
    const float* W1   = (const float*)d_in[22];
    const float* b1   = (const float*)d_in[23];
    const float* W2   = (const float*)d_in[24];
    const float* b2   = (const float*)d_in[25];

    float* ws    = (float*)d_ws;
    float* x     = ws;              // 65536
    float* h0cat = ws + 65536;      // 131072
    float* h1cat = ws + 196608;     // 131072
    float* pA    = ws + 327680;     // 262144
    float* pB    = ws + 589824;     // 262144
    float* S     = ws;              // 262144 (aliases x/h0cat; dead by then)
    float* csum  = ws + 262144;     // 512
    float* out   = (float*)d_out;

    embed_kernel<<<512, 128, 0, stream>>>(wid, tgi, wemb, temb, x);

    gemm2<<<dim3(8,8,2), 256, 0, stream>>>(x, 128, Wih0f, Wih0b, 128, 0,
                                           bih0f, bih0b, bhh0f, bhh0b,
                                           pA, pB, 128, 1.0f);
    lstm_kernel<<<2, 1024, 0, stream>>>(pA, pB, Whh0f, Whh0b, h0, c0, h0cat, 0);

    gemm2<<<dim3(8,8,2), 256, 0, stream>>>(h0cat, 256, Wih1f, Wih1b, 256, 0,
                                           bih1f, bih1b, bhh1f, bhh1b,
                                           pA, pB, 256, 1.0f);
    lstm_kernel<<<2, 1024, 0, stream>>>(pA, pB, Whh1f, Whh1b, h0, c0, h1cat, 1);

    gemm2<<<dim3(8,8,2), 256, 0, stream>>>(h1cat, 256, W1, W1, 512, 256,
                                           b1, nullptr, nullptr, nullptr,
                                           pA, pB, 256, TWO_LOG2E);

    score_kernel<<<dim3(16,16), 256, 0, stream>>>(pA, pB, W2, b2, S);
    colsum_kernel<<<16, 256, 0, stream>>>(S, csum);
    softmax_kernel<<<512, 256, 0, stream>>>(S, csum, out);
}